// Round 9
// baseline (412.919 us; speedup 1.0000x reference)
//
#include <hip/hip_runtime.h>
#include <hip/hip_bf16.h>

#define NN 50000
#define NE 1600000
#define D 128
#define MAXDEG 80   // Poisson(32): P(deg>80)*NN ~ 2.5e-8; guarded anyway
#define EPT 16      // edges per thread in scatter

__device__ __forceinline__ void fma4(float4& acc, float s, const float4& w) {
  acc.x = fmaf(s, w.x, acc.x);
  acc.y = fmaf(s, w.y, acc.y);
  acc.z = fmaf(s, w.z, acc.z);
  acc.w = fmaf(s, w.w, acc.w);
}

// ---------------------------------------------------------------------------
// K1: fused slot-scatter. EPT edges/thread, all atomics issued before stores
// (atomic-with-return is coherence-point throughput-bound ~18/ns).
// ---------------------------------------------------------------------------
__global__ __launch_bounds__(256) void k_scatter(const int* __restrict__ dst,
                                                 const int* __restrict__ src,
                                                 const int* __restrict__ ea,
                                                 int* __restrict__ cnt,
                                                 unsigned* __restrict__ packed) {
  const int gid = blockIdx.x * 256 + threadIdx.x;
  const int e0 = gid * EPT;
  if (e0 >= NE) return;

  int d[EPT], rec[EPT];
  {
    const int4* dp = (const int4*)(dst + e0);
    const int4* sp = (const int4*)(src + e0);
    const int4* ap = (const int4*)(ea + 3 * e0);
    int a[3 * EPT];
#pragma unroll
    for (int q = 0; q < (3 * EPT) / 4; ++q) {
      const int4 v = ap[q];
      a[4 * q + 0] = v.x; a[4 * q + 1] = v.y; a[4 * q + 2] = v.z; a[4 * q + 3] = v.w;
    }
#pragma unroll
    for (int q = 0; q < EPT / 4; ++q) {
      const int4 dv = dp[q];
      const int4 sv = sp[q];
      d[4 * q + 0] = dv.x; d[4 * q + 1] = dv.y; d[4 * q + 2] = dv.z; d[4 * q + 3] = dv.w;
      rec[4 * q + 0] = sv.x; rec[4 * q + 1] = sv.y; rec[4 * q + 2] = sv.z; rec[4 * q + 3] = sv.w;
    }
#pragma unroll
    for (int q = 0; q < EPT; ++q) {
      const int cb = (a[3 * q] * 5 + a[3 * q + 1]) * 5 + a[3 * q + 2];
      rec[q] |= cb << 16;
    }
  }

  int pos[EPT];
#pragma unroll
  for (int q = 0; q < EPT; ++q) pos[q] = atomicAdd(&cnt[d[q]], 1);

#pragma unroll
  for (int q = 0; q < EPT; ++q)
    if (pos[q] < MAXDEG)
      packed[(size_t)d[q] * MAXDEG + pos[q]] = (unsigned)rec[q];
}

// ---------------------------------------------------------------------------
// K2: per-node aggregation. 1024-thr blocks, 32 nodes/block; the combined
// bond table (125*128 fp32 = 62.5 KiB) lives in LDS -> halves L2 line
// requests per edge (16 -> 8). x gathered from global (L2/L3).
// ---------------------------------------------------------------------------
__global__ __launch_bounds__(1024, 8) void k_agg(const float* __restrict__ x,
                                                 const float* __restrict__ bemb,
                                                 const float* __restrict__ epsp,
                                                 const int* __restrict__ cnt,
                                                 const unsigned* __restrict__ packed,
                                                 float* __restrict__ hbuf) {
  __shared__ float sctab[125 * D];  // 62.5 KiB
  const int tid = threadIdx.x;
  // build combined table in LDS: ctab[c][k] = e0[c/25] + e1[(c%25)/5] + e2[c%5]
  for (int i = tid; i < 125 * D; i += 1024) {
    const int c = i >> 7;
    const int k = i & 127;
    sctab[i] = bemb[(c / 25) * D + k] + bemb[(5 + (c % 25) / 5) * D + k] +
               bemb[(10 + c % 5) * D + k];
  }
  __syncthreads();

  const int lane = tid & 31;
  const int n = blockIdx.x * 32 + (tid >> 5);
  if (n >= NN) return;  // no barriers below
  const int col = lane << 2;

  const unsigned* seg = packed + (size_t)n * MAXDEG;
  const int deg = min(cnt[n], MAXDEG);
  float4 acc = make_float4(0.f, 0.f, 0.f, 0.f);

  for (int jb = 0; jb < deg; jb += 32) {
    const int rem = min(32, deg - jb);
    const int pk = (jb + lane < deg) ? (int)seg[jb + lane] : 0;
    int t = 0;
    for (; t + 8 <= rem; t += 8) {
      unsigned p[8];
#pragma unroll
      for (int i = 0; i < 8; ++i) p[i] = (unsigned)__shfl(pk, t + i, 32);
      float4 xs[8];
#pragma unroll
      for (int i = 0; i < 8; ++i)
        xs[i] = *(const float4*)(x + (size_t)(p[i] & 0xFFFF) * D + col);
#pragma unroll
      for (int i = 0; i < 8; ++i) {
        const float4 ev = *(const float4*)(sctab + ((p[i] >> 16) & 0x7F) * D + col);
        acc.x += fmaxf(xs[i].x + ev.x, 0.f);
        acc.y += fmaxf(xs[i].y + ev.y, 0.f);
        acc.z += fmaxf(xs[i].z + ev.z, 0.f);
        acc.w += fmaxf(xs[i].w + ev.w, 0.f);
      }
    }
    for (; t < rem; ++t) {
      const unsigned p = (unsigned)__shfl(pk, t, 32);
      const float4 ev = *(const float4*)(sctab + ((p >> 16) & 0x7F) * D + col);
      const float4 xv = *(const float4*)(x + (size_t)(p & 0xFFFF) * D + col);
      acc.x += fmaxf(xv.x + ev.x, 0.f);
      acc.y += fmaxf(xv.y + ev.y, 0.f);
      acc.z += fmaxf(xv.z + ev.z, 0.f);
      acc.w += fmaxf(xv.w + ev.w, 0.f);
    }
  }

  const float eps1 = 1.0f + epsp[0];
  const float4 xv = *(const float4*)(x + (size_t)n * D + col);
  acc.x += eps1 * xv.x;
  acc.y += eps1 * xv.y;
  acc.z += eps1 * xv.z;
  acc.w += eps1 * xv.w;
  *(float4*)(hbuf + (size_t)n * D + col) = acc;
}

// ---------------------------------------------------------------------------
// K3: h1 = h @ W1 + b1 (in-place) + fused BN sum/sumsq. (unchanged control)
// ---------------------------------------------------------------------------
__global__ __launch_bounds__(256, 2) void k_gemm1(const float* __restrict__ hbuf,
                                                  const float* __restrict__ W1,
                                                  const float* __restrict__ b1,
                                                  float* __restrict__ h1,
                                                  float* __restrict__ gsum,
                                                  float* __restrict__ gsumsq) {
  __shared__ float shT[64 * 64];   // [k][row], 16 KB
  __shared__ float sW[64 * 128];   // [k][col], 32 KB

  const int tid = threadIdx.x;
  const int row0 = blockIdx.x * 64;
  const int cg = tid & 31;
  const int rt = tid >> 5;
  const int cbase = cg * 4;
  const int rbase = rt * 8;

  float4 acc[8];
  const float4 bias = *(const float4*)(b1 + cbase);
#pragma unroll
  for (int r = 0; r < 8; ++r) acc[r] = bias;

  for (int kh = 0; kh < 2; ++kh) {
    __syncthreads();
    for (int i = tid; i < 1024; i += 256) {
      const int r = i & 63;
      const int kc = (i >> 6) << 2;
      const int gr = row0 + r;
      float4 v = make_float4(0.f, 0.f, 0.f, 0.f);
      if (gr < NN) v = *(const float4*)(hbuf + (size_t)gr * D + kh * 64 + kc);
      shT[(kc + 0) * 64 + r] = v.x;
      shT[(kc + 1) * 64 + r] = v.y;
      shT[(kc + 2) * 64 + r] = v.z;
      shT[(kc + 3) * 64 + r] = v.w;
    }
    for (int i = tid; i < 2048; i += 256) {
      const int k = i >> 5;
      const int c4 = (i & 31) << 2;
      *(float4*)(sW + k * 128 + c4) = *(const float4*)(W1 + (size_t)(kh * 64 + k) * D + c4);
    }
    __syncthreads();
    for (int k = 0; k < 64; ++k) {
      const float4 a_lo = *(const float4*)(shT + k * 64 + rbase);
      const float4 a_hi = *(const float4*)(shT + k * 64 + rbase + 4);
      const float4 w = *(const float4*)(sW + k * 128 + cbase);
      fma4(acc[0], a_lo.x, w); fma4(acc[1], a_lo.y, w);
      fma4(acc[2], a_lo.z, w); fma4(acc[3], a_lo.w, w);
      fma4(acc[4], a_hi.x, w); fma4(acc[5], a_hi.y, w);
      fma4(acc[6], a_hi.z, w); fma4(acc[7], a_hi.w, w);
    }
  }

  float4 cs = make_float4(0.f, 0.f, 0.f, 0.f);
  float4 cq = make_float4(0.f, 0.f, 0.f, 0.f);
#pragma unroll
  for (int r = 0; r < 8; ++r) {
    const int gr = row0 + rbase + r;
    if (gr < NN) {
      *(float4*)(h1 + (size_t)gr * D + cbase) = acc[r];
      cs.x += acc[r].x; cs.y += acc[r].y; cs.z += acc[r].z; cs.w += acc[r].w;
      cq.x += acc[r].x * acc[r].x; cq.y += acc[r].y * acc[r].y;
      cq.z += acc[r].z * acc[r].z; cq.w += acc[r].w * acc[r].w;
    }
  }
  __syncthreads();
  float* ssum = shT;
  float* ssq = shT + 128;
  if (tid < 128) { ssum[tid] = 0.f; ssq[tid] = 0.f; }
  __syncthreads();
  atomicAdd(&ssum[cbase + 0], cs.x);
  atomicAdd(&ssum[cbase + 1], cs.y);
  atomicAdd(&ssum[cbase + 2], cs.z);
  atomicAdd(&ssum[cbase + 3], cs.w);
  atomicAdd(&ssq[cbase + 0], cq.x);
  atomicAdd(&ssq[cbase + 1], cq.y);
  atomicAdd(&ssq[cbase + 2], cq.z);
  atomicAdd(&ssq[cbase + 3], cq.w);
  __syncthreads();
  if (tid < 128) {
    atomicAdd(&gsum[tid], ssum[tid]);
    atomicAdd(&gsumsq[tid], ssq[tid]);
  }
}

// ---------------------------------------------------------------------------
// K4: out = relu(BN(h1)) @ W2 + b2. (unchanged control)
// ---------------------------------------------------------------------------
__global__ __launch_bounds__(256, 2) void k_gemm2(const float* __restrict__ hbuf,
                                                  const float* __restrict__ gsum,
                                                  const float* __restrict__ gsq,
                                                  const float* __restrict__ gamma,
                                                  const float* __restrict__ beta,
                                                  const float* __restrict__ W2,
                                                  const float* __restrict__ b2,
                                                  float* __restrict__ out) {
  __shared__ float shT[64 * 64];
  __shared__ float sW[64 * 128];

  const int tid = threadIdx.x;
  const int row0 = blockIdx.x * 64;
  const int cg = tid & 31;
  const int rt = tid >> 5;
  const int cbase = cg * 4;
  const int rbase = rt * 8;
  const float invN = 1.0f / (float)NN;

  float4 acc[8];
  const float4 bias = *(const float4*)(b2 + cbase);
#pragma unroll
  for (int r = 0; r < 8; ++r) acc[r] = bias;

  for (int kh = 0; kh < 2; ++kh) {
    __syncthreads();
    for (int i = tid; i < 1024; i += 256) {
      const int r = i & 63;
      const int kc = (i >> 6) << 2;
      const int gr = row0 + r;
      const int kk = kh * 64 + kc;
      const float4 gs = *(const float4*)(gsum + kk);
      const float4 gq = *(const float4*)(gsq + kk);
      const float4 gm = *(const float4*)(gamma + kk);
      const float4 bt = *(const float4*)(beta + kk);
      const float m0 = gs.x * invN, m1 = gs.y * invN, m2 = gs.z * invN, m3 = gs.w * invN;
      const float A0 = gm.x * rsqrtf(gq.x * invN - m0 * m0 + 1e-5f);
      const float A1 = gm.y * rsqrtf(gq.y * invN - m1 * m1 + 1e-5f);
      const float A2 = gm.z * rsqrtf(gq.z * invN - m2 * m2 + 1e-5f);
      const float A3 = gm.w * rsqrtf(gq.w * invN - m3 * m3 + 1e-5f);
      float4 v = make_float4(0.f, 0.f, 0.f, 0.f);
      if (gr < NN) {
        const float4 h = *(const float4*)(hbuf + (size_t)gr * D + kk);
        v.x = fmaxf(fmaf(h.x - m0, A0, bt.x), 0.f);
        v.y = fmaxf(fmaf(h.y - m1, A1, bt.y), 0.f);
        v.z = fmaxf(fmaf(h.z - m2, A2, bt.z), 0.f);
        v.w = fmaxf(fmaf(h.w - m3, A3, bt.w), 0.f);
      }
      shT[(kc + 0) * 64 + r] = v.x;
      shT[(kc + 1) * 64 + r] = v.y;
      shT[(kc + 2) * 64 + r] = v.z;
      shT[(kc + 3) * 64 + r] = v.w;
    }
    for (int i = tid; i < 2048; i += 256) {
      const int k = i >> 5;
      const int c4 = (i & 31) << 2;
      *(float4*)(sW + k * 128 + c4) = *(const float4*)(W2 + (size_t)(kh * 64 + k) * D + c4);
    }
    __syncthreads();
    for (int k = 0; k < 64; ++k) {
      const float4 a_lo = *(const float4*)(shT + k * 64 + rbase);
      const float4 a_hi = *(const float4*)(shT + k * 64 + rbase + 4);
      const float4 w = *(const float4*)(sW + k * 128 + cbase);
      fma4(acc[0], a_lo.x, w); fma4(acc[1], a_lo.y, w);
      fma4(acc[2], a_lo.z, w); fma4(acc[3], a_lo.w, w);
      fma4(acc[4], a_hi.x, w); fma4(acc[5], a_hi.y, w);
      fma4(acc[6], a_hi.z, w); fma4(acc[7], a_hi.w, w);
    }
  }

#pragma unroll
  for (int r = 0; r < 8; ++r) {
    const int gr = row0 + rbase + r;
    if (gr < NN) *(float4*)(out + (size_t)gr * D + cbase) = acc[r];
  }
}

extern "C" void kernel_launch(void* const* d_in, const int* in_sizes, int n_in,
                              void* d_out, int out_size, void* d_ws, size_t ws_size,
                              hipStream_t stream) {
  const float* x    = (const float*)d_in[0];
  const int* ea     = (const int*)d_in[1];
  const int* src    = (const int*)d_in[2];
  const int* dst    = (const int*)d_in[3];
  const float* bemb = (const float*)d_in[4];
  const float* epsp = (const float*)d_in[5];
  const float* W1   = (const float*)d_in[6];
  const float* b1   = (const float*)d_in[7];
  const float* gam  = (const float*)d_in[8];
  const float* bet  = (const float*)d_in[9];
  const float* W2   = (const float*)d_in[10];
  const float* b2   = (const float*)d_in[11];
  float* out = (float*)d_out;

  float* ws        = (float*)d_ws;
  float* hbuf      = ws;                                 // NN*D
  int* cnt         = (int*)(ws + (size_t)NN * D);        // NN    (zeroed)
  float* gsum      = ws + (size_t)NN * D + NN;           // 128   (zeroed)
  float* gsumsq    = gsum + D;                           // 128   (zeroed)
  unsigned* packed = (unsigned*)(gsumsq + D);            // NN*MAXDEG (16 MB)

  hipMemsetAsync(cnt, 0, (size_t)(NN + 2 * D) * sizeof(int), stream);

  k_scatter<<<(NE / EPT + 255) / 256, 256, 0, stream>>>(dst, src, ea, cnt, packed);
  k_agg<<<(NN + 31) / 32, 1024, 0, stream>>>(x, bemb, epsp, cnt, packed, hbuf);
  k_gemm1<<<(NN + 63) / 64, 256, 0, stream>>>(hbuf, W1, b1, hbuf, gsum, gsumsq);
  k_gemm2<<<(NN + 63) / 64, 256, 0, stream>>>(hbuf, gsum, gsumsq, gam, bet, W2, b2, out);
}

// Round 10
// 377.397 us; speedup vs baseline: 1.0941x; 1.0941x over previous
//
#include <hip/hip_runtime.h>
#include <hip/hip_bf16.h>

#define NN 50000
#define NE 1600000
#define D 128
#define MAXDEG 80   // Poisson(32): P(deg>80)*NN ~ 2.5e-8; guarded anyway
#define EPT 16      // edges per thread in scatter

__device__ __forceinline__ void fma4(float4& acc, float s, const float4& w) {
  acc.x = fmaf(s, w.x, acc.x);
  acc.y = fmaf(s, w.y, acc.y);
  acc.z = fmaf(s, w.z, acc.z);
  acc.w = fmaf(s, w.w, acc.w);
}

__device__ __forceinline__ unsigned short f2bf(float f) {
  unsigned u = __float_as_uint(f);
  u += 0x7FFFu + ((u >> 16) & 1u);  // round-to-nearest-even
  return (unsigned short)(u >> 16);
}
__device__ __forceinline__ float bf2f(unsigned short h) {
  return __uint_as_float((unsigned)h << 16);
}

// ---------------------------------------------------------------------------
// K0: prep — xh = bf16(x) (halves gather miss bytes) + build combined bond
// table ctab[combo][k] in global (L2-hot; hit-requests proven free in R9).
// ---------------------------------------------------------------------------
__global__ __launch_bounds__(256) void k_half(const float* __restrict__ x,
                                              const float* __restrict__ bemb,
                                              ushort* __restrict__ xh,
                                              float* __restrict__ ctab) {
  const int gid = blockIdx.x * 256 + threadIdx.x;

  if (gid < 125 * D) {
    const int c = gid >> 7;
    const int k = gid & 127;
    ctab[gid] = bemb[(c / 25) * D + k] + bemb[(5 + (c % 25) / 5) * D + k] +
                bemb[(10 + c % 5) * D + k];
  }

  const int i4 = gid * 4;
  if (i4 < NN * D) {
    const float4 v = *(const float4*)(x + i4);
    ushort4 h;
    h.x = f2bf(v.x); h.y = f2bf(v.y); h.z = f2bf(v.z); h.w = f2bf(v.w);
    *(ushort4*)(xh + i4) = h;
  }
}

// ---------------------------------------------------------------------------
// K1: fused slot-scatter. EPT edges/thread, all atomics issued before stores.
// ---------------------------------------------------------------------------
__global__ __launch_bounds__(256) void k_scatter(const int* __restrict__ dst,
                                                 const int* __restrict__ src,
                                                 const int* __restrict__ ea,
                                                 int* __restrict__ cnt,
                                                 unsigned* __restrict__ packed) {
  const int gid = blockIdx.x * 256 + threadIdx.x;
  const int e0 = gid * EPT;
  if (e0 >= NE) return;

  int d[EPT], rec[EPT];
  {
    const int4* dp = (const int4*)(dst + e0);
    const int4* sp = (const int4*)(src + e0);
    const int4* ap = (const int4*)(ea + 3 * e0);
    int a[3 * EPT];
#pragma unroll
    for (int q = 0; q < (3 * EPT) / 4; ++q) {
      const int4 v = ap[q];
      a[4 * q + 0] = v.x; a[4 * q + 1] = v.y; a[4 * q + 2] = v.z; a[4 * q + 3] = v.w;
    }
#pragma unroll
    for (int q = 0; q < EPT / 4; ++q) {
      const int4 dv = dp[q];
      const int4 sv = sp[q];
      d[4 * q + 0] = dv.x; d[4 * q + 1] = dv.y; d[4 * q + 2] = dv.z; d[4 * q + 3] = dv.w;
      rec[4 * q + 0] = sv.x; rec[4 * q + 1] = sv.y; rec[4 * q + 2] = sv.z; rec[4 * q + 3] = sv.w;
    }
#pragma unroll
    for (int q = 0; q < EPT; ++q) {
      const int cb = (a[3 * q] * 5 + a[3 * q + 1]) * 5 + a[3 * q + 2];
      rec[q] |= cb << 16;
    }
  }

  int pos[EPT];
#pragma unroll
  for (int q = 0; q < EPT; ++q) pos[q] = atomicAdd(&cnt[d[q]], 1);

#pragma unroll
  for (int q = 0; q < EPT; ++q)
    if (pos[q] < MAXDEG)
      packed[(size_t)d[q] * MAXDEG + pos[q]] = (unsigned)rec[q];
}

// ---------------------------------------------------------------------------
// K2: per-node aggregation (R8 structure). 32 lanes/node, 8 nodes/block;
// neighbor rows gathered as bf16 ushort4 (8 B/lane -> half the L2-miss bytes);
// ctab fp32 from global (L2-hot). Self term uses exact fp32 x.
// ---------------------------------------------------------------------------
__global__ __launch_bounds__(256, 4) void k_agg(const float* __restrict__ x,
                                                const ushort* __restrict__ xh,
                                                const float* __restrict__ ctab,
                                                const float* __restrict__ epsp,
                                                const int* __restrict__ cnt,
                                                const unsigned* __restrict__ packed,
                                                float* __restrict__ hbuf) {
  const int lane = threadIdx.x & 31;
  const int n = blockIdx.x * 8 + (threadIdx.x >> 5);  // 6250*8 = NN exactly
  const int col = lane << 2;

  const unsigned* seg = packed + (size_t)n * MAXDEG;
  const int deg = min(cnt[n], MAXDEG);
  float4 acc = make_float4(0.f, 0.f, 0.f, 0.f);

  for (int jb = 0; jb < deg; jb += 32) {
    const int rem = min(32, deg - jb);
    const int pk = (jb + lane < deg) ? (int)seg[jb + lane] : 0;
    int t = 0;
    for (; t + 8 <= rem; t += 8) {
      unsigned p[8];
#pragma unroll
      for (int i = 0; i < 8; ++i) p[i] = (unsigned)__shfl(pk, t + i, 32);
      ushort4 xs[8];
#pragma unroll
      for (int i = 0; i < 8; ++i)
        xs[i] = *(const ushort4*)(xh + (size_t)(p[i] & 0xFFFF) * D + col);
#pragma unroll
      for (int i = 0; i < 8; ++i) {
        const float4 ev = *(const float4*)(ctab + ((p[i] >> 16) & 0x7F) * D + col);
        acc.x += fmaxf(bf2f(xs[i].x) + ev.x, 0.f);
        acc.y += fmaxf(bf2f(xs[i].y) + ev.y, 0.f);
        acc.z += fmaxf(bf2f(xs[i].z) + ev.z, 0.f);
        acc.w += fmaxf(bf2f(xs[i].w) + ev.w, 0.f);
      }
    }
    for (; t < rem; ++t) {
      const unsigned p = (unsigned)__shfl(pk, t, 32);
      const ushort4 xv = *(const ushort4*)(xh + (size_t)(p & 0xFFFF) * D + col);
      const float4 ev = *(const float4*)(ctab + ((p >> 16) & 0x7F) * D + col);
      acc.x += fmaxf(bf2f(xv.x) + ev.x, 0.f);
      acc.y += fmaxf(bf2f(xv.y) + ev.y, 0.f);
      acc.z += fmaxf(bf2f(xv.z) + ev.z, 0.f);
      acc.w += fmaxf(bf2f(xv.w) + ev.w, 0.f);
    }
  }

  const float eps1 = 1.0f + epsp[0];
  const float4 xv = *(const float4*)(x + (size_t)n * D + col);
  acc.x += eps1 * xv.x;
  acc.y += eps1 * xv.y;
  acc.z += eps1 * xv.z;
  acc.w += eps1 * xv.w;
  *(float4*)(hbuf + (size_t)n * D + col) = acc;
}

// ---------------------------------------------------------------------------
// K3: h1 = h @ W1 + b1 (in-place) + fused BN sum/sumsq. (unchanged control)
// ---------------------------------------------------------------------------
__global__ __launch_bounds__(256, 2) void k_gemm1(const float* __restrict__ hbuf,
                                                  const float* __restrict__ W1,
                                                  const float* __restrict__ b1,
                                                  float* __restrict__ h1,
                                                  float* __restrict__ gsum,
                                                  float* __restrict__ gsumsq) {
  __shared__ float shT[64 * 64];   // [k][row], 16 KB
  __shared__ float sW[64 * 128];   // [k][col], 32 KB

  const int tid = threadIdx.x;
  const int row0 = blockIdx.x * 64;
  const int cg = tid & 31;
  const int rt = tid >> 5;
  const int cbase = cg * 4;
  const int rbase = rt * 8;

  float4 acc[8];
  const float4 bias = *(const float4*)(b1 + cbase);
#pragma unroll
  for (int r = 0; r < 8; ++r) acc[r] = bias;

  for (int kh = 0; kh < 2; ++kh) {
    __syncthreads();
    for (int i = tid; i < 1024; i += 256) {
      const int r = i & 63;
      const int kc = (i >> 6) << 2;
      const int gr = row0 + r;
      float4 v = make_float4(0.f, 0.f, 0.f, 0.f);
      if (gr < NN) v = *(const float4*)(hbuf + (size_t)gr * D + kh * 64 + kc);
      shT[(kc + 0) * 64 + r] = v.x;
      shT[(kc + 1) * 64 + r] = v.y;
      shT[(kc + 2) * 64 + r] = v.z;
      shT[(kc + 3) * 64 + r] = v.w;
    }
    for (int i = tid; i < 2048; i += 256) {
      const int k = i >> 5;
      const int c4 = (i & 31) << 2;
      *(float4*)(sW + k * 128 + c4) = *(const float4*)(W1 + (size_t)(kh * 64 + k) * D + c4);
    }
    __syncthreads();
    for (int k = 0; k < 64; ++k) {
      const float4 a_lo = *(const float4*)(shT + k * 64 + rbase);
      const float4 a_hi = *(const float4*)(shT + k * 64 + rbase + 4);
      const float4 w = *(const float4*)(sW + k * 128 + cbase);
      fma4(acc[0], a_lo.x, w); fma4(acc[1], a_lo.y, w);
      fma4(acc[2], a_lo.z, w); fma4(acc[3], a_lo.w, w);
      fma4(acc[4], a_hi.x, w); fma4(acc[5], a_hi.y, w);
      fma4(acc[6], a_hi.z, w); fma4(acc[7], a_hi.w, w);
    }
  }

  float4 cs = make_float4(0.f, 0.f, 0.f, 0.f);
  float4 cq = make_float4(0.f, 0.f, 0.f, 0.f);
#pragma unroll
  for (int r = 0; r < 8; ++r) {
    const int gr = row0 + rbase + r;
    if (gr < NN) {
      *(float4*)(h1 + (size_t)gr * D + cbase) = acc[r];
      cs.x += acc[r].x; cs.y += acc[r].y; cs.z += acc[r].z; cs.w += acc[r].w;
      cq.x += acc[r].x * acc[r].x; cq.y += acc[r].y * acc[r].y;
      cq.z += acc[r].z * acc[r].z; cq.w += acc[r].w * acc[r].w;
    }
  }
  __syncthreads();
  float* ssum = shT;
  float* ssq = shT + 128;
  if (tid < 128) { ssum[tid] = 0.f; ssq[tid] = 0.f; }
  __syncthreads();
  atomicAdd(&ssum[cbase + 0], cs.x);
  atomicAdd(&ssum[cbase + 1], cs.y);
  atomicAdd(&ssum[cbase + 2], cs.z);
  atomicAdd(&ssum[cbase + 3], cs.w);
  atomicAdd(&ssq[cbase + 0], cq.x);
  atomicAdd(&ssq[cbase + 1], cq.y);
  atomicAdd(&ssq[cbase + 2], cq.z);
  atomicAdd(&ssq[cbase + 3], cq.w);
  __syncthreads();
  if (tid < 128) {
    atomicAdd(&gsum[tid], ssum[tid]);
    atomicAdd(&gsumsq[tid], ssq[tid]);
  }
}

// ---------------------------------------------------------------------------
// K4: out = relu(BN(h1)) @ W2 + b2. (unchanged control)
// ---------------------------------------------------------------------------
__global__ __launch_bounds__(256, 2) void k_gemm2(const float* __restrict__ hbuf,
                                                  const float* __restrict__ gsum,
                                                  const float* __restrict__ gsq,
                                                  const float* __restrict__ gamma,
                                                  const float* __restrict__ beta,
                                                  const float* __restrict__ W2,
                                                  const float* __restrict__ b2,
                                                  float* __restrict__ out) {
  __shared__ float shT[64 * 64];
  __shared__ float sW[64 * 128];

  const int tid = threadIdx.x;
  const int row0 = blockIdx.x * 64;
  const int cg = tid & 31;
  const int rt = tid >> 5;
  const int cbase = cg * 4;
  const int rbase = rt * 8;
  const float invN = 1.0f / (float)NN;

  float4 acc[8];
  const float4 bias = *(const float4*)(b2 + cbase);
#pragma unroll
  for (int r = 0; r < 8; ++r) acc[r] = bias;

  for (int kh = 0; kh < 2; ++kh) {
    __syncthreads();
    for (int i = tid; i < 1024; i += 256) {
      const int r = i & 63;
      const int kc = (i >> 6) << 2;
      const int gr = row0 + r;
      const int kk = kh * 64 + kc;
      const float4 gs = *(const float4*)(gsum + kk);
      const float4 gq = *(const float4*)(gsq + kk);
      const float4 gm = *(const float4*)(gamma + kk);
      const float4 bt = *(const float4*)(beta + kk);
      const float m0 = gs.x * invN, m1 = gs.y * invN, m2 = gs.z * invN, m3 = gs.w * invN;
      const float A0 = gm.x * rsqrtf(gq.x * invN - m0 * m0 + 1e-5f);
      const float A1 = gm.y * rsqrtf(gq.y * invN - m1 * m1 + 1e-5f);
      const float A2 = gm.z * rsqrtf(gq.z * invN - m2 * m2 + 1e-5f);
      const float A3 = gm.w * rsqrtf(gq.w * invN - m3 * m3 + 1e-5f);
      float4 v = make_float4(0.f, 0.f, 0.f, 0.f);
      if (gr < NN) {
        const float4 h = *(const float4*)(hbuf + (size_t)gr * D + kk);
        v.x = fmaxf(fmaf(h.x - m0, A0, bt.x), 0.f);
        v.y = fmaxf(fmaf(h.y - m1, A1, bt.y), 0.f);
        v.z = fmaxf(fmaf(h.z - m2, A2, bt.z), 0.f);
        v.w = fmaxf(fmaf(h.w - m3, A3, bt.w), 0.f);
      }
      shT[(kc + 0) * 64 + r] = v.x;
      shT[(kc + 1) * 64 + r] = v.y;
      shT[(kc + 2) * 64 + r] = v.z;
      shT[(kc + 3) * 64 + r] = v.w;
    }
    for (int i = tid; i < 2048; i += 256) {
      const int k = i >> 5;
      const int c4 = (i & 31) << 2;
      *(float4*)(sW + k * 128 + c4) = *(const float4*)(W2 + (size_t)(kh * 64 + k) * D + c4);
    }
    __syncthreads();
    for (int k = 0; k < 64; ++k) {
      const float4 a_lo = *(const float4*)(shT + k * 64 + rbase);
      const float4 a_hi = *(const float4*)(shT + k * 64 + rbase + 4);
      const float4 w = *(const float4*)(sW + k * 128 + cbase);
      fma4(acc[0], a_lo.x, w); fma4(acc[1], a_lo.y, w);
      fma4(acc[2], a_lo.z, w); fma4(acc[3], a_lo.w, w);
      fma4(acc[4], a_hi.x, w); fma4(acc[5], a_hi.y, w);
      fma4(acc[6], a_hi.z, w); fma4(acc[7], a_hi.w, w);
    }
  }

#pragma unroll
  for (int r = 0; r < 8; ++r) {
    const int gr = row0 + rbase + r;
    if (gr < NN) *(float4*)(out + (size_t)gr * D + cbase) = acc[r];
  }
}

extern "C" void kernel_launch(void* const* d_in, const int* in_sizes, int n_in,
                              void* d_out, int out_size, void* d_ws, size_t ws_size,
                              hipStream_t stream) {
  const float* x    = (const float*)d_in[0];
  const int* ea     = (const int*)d_in[1];
  const int* src    = (const int*)d_in[2];
  const int* dst    = (const int*)d_in[3];
  const float* bemb = (const float*)d_in[4];
  const float* epsp = (const float*)d_in[5];
  const float* W1   = (const float*)d_in[6];
  const float* b1   = (const float*)d_in[7];
  const float* gam  = (const float*)d_in[8];
  const float* bet  = (const float*)d_in[9];
  const float* W2   = (const float*)d_in[10];
  const float* b2   = (const float*)d_in[11];
  float* out = (float*)d_out;

  float* ws        = (float*)d_ws;
  float* hbuf      = ws;                                 // NN*D fp32
  int* cnt         = (int*)(ws + (size_t)NN * D);        // NN    (zeroed)
  float* gsum      = ws + (size_t)NN * D + NN;           // 128   (zeroed)
  float* gsumsq    = gsum + D;                           // 128   (zeroed)
  float* ctab      = gsumsq + D;                         // 125*128
  ushort* xh       = (ushort*)(ctab + 125 * D);          // NN*D bf16 (12.8 MB)
  unsigned* packed = (unsigned*)(xh + (size_t)NN * D);   // NN*MAXDEG (16 MB)

  hipMemsetAsync(cnt, 0, (size_t)(NN + 2 * D) * sizeof(int), stream);

  k_half<<<(NN * D / 4 + 255) / 256, 256, 0, stream>>>(x, bemb, xh, ctab);
  k_scatter<<<(NE / EPT + 255) / 256, 256, 0, stream>>>(dst, src, ea, cnt, packed);
  k_agg<<<NN / 8, 256, 0, stream>>>(x, xh, ctab, epsp, cnt, packed, hbuf);
  k_gemm1<<<(NN + 63) / 64, 256, 0, stream>>>(hbuf, W1, b1, hbuf, gsum, gsumsq);
  k_gemm2<<<(NN + 63) / 64, 256, 0, stream>>>(hbuf, gsum, gsumsq, gam, bet, W2, b2, out);
}

// Round 11
// 320.654 us; speedup vs baseline: 1.2877x; 1.1770x over previous
//
#include <hip/hip_runtime.h>
#include <hip/hip_bf16.h>

#define NN 50000
#define NE 1600000
#define D 128
#define NB 196      // coarse buckets of 256 nodes (196*256 = 50176 >= NN)
#define CAP 9216    // bucket capacity; Poisson(8163), sd~90 -> +11.7 sd safe
#define EPT 16      // edges per thread in k_bin

__device__ __forceinline__ void fma4(float4& acc, float s, const float4& w) {
  acc.x = fmaf(s, w.x, acc.x);
  acc.y = fmaf(s, w.y, acc.y);
  acc.z = fmaf(s, w.z, acc.z);
  acc.w = fmaf(s, w.w, acc.w);
}

__device__ __forceinline__ unsigned short f2bf(float f) {
  unsigned u = __float_as_uint(f);
  u += 0x7FFFu + ((u >> 16) & 1u);
  return (unsigned short)(u >> 16);
}
__device__ __forceinline__ float bf2f(unsigned short h) {
  return __uint_as_float((unsigned)h << 16);
}

// ---------------------------------------------------------------------------
// K0: prep — xh = bf16(x) + combined bond table ctab (global, L2-hot).
// ---------------------------------------------------------------------------
__global__ __launch_bounds__(256) void k_half(const float* __restrict__ x,
                                              const float* __restrict__ bemb,
                                              ushort* __restrict__ xh,
                                              float* __restrict__ ctab) {
  const int gid = blockIdx.x * 256 + threadIdx.x;

  if (gid < 125 * D) {
    const int c = gid >> 7;
    const int k = gid & 127;
    ctab[gid] = bemb[(c / 25) * D + k] + bemb[(5 + (c % 25) / 5) * D + k] +
                bemb[(10 + c % 5) * D + k];
  }

  const int i4 = gid * 4;
  if (i4 < NN * D) {
    const float4 v = *(const float4*)(x + i4);
    ushort4 h;
    h.x = f2bf(v.x); h.y = f2bf(v.y); h.z = f2bf(v.z); h.w = f2bf(v.w);
    *(ushort4*)(xh + i4) = h;
  }
}

// ---------------------------------------------------------------------------
// K1: coarse bin by dst>>8. Per-block LDS counts -> ONE global atomic per
// (block,bucket) -> dense run writes (~84 B runs vs 64 B/edge before).
// record = src | cb<<16 | (dst&255)<<23  (31 bits)
// ---------------------------------------------------------------------------
__global__ __launch_bounds__(256) void k_bin(const int* __restrict__ dst,
                                             const int* __restrict__ src,
                                             const int* __restrict__ ea,
                                             int* __restrict__ bucketCnt,
                                             unsigned* __restrict__ staging) {
  __shared__ int lcnt[NB], gbase[NB], lcur[NB];
  const int tid = threadIdx.x;
  for (int i = tid; i < NB; i += 256) { lcnt[i] = 0; lcur[i] = 0; }
  __syncthreads();

  const int gid = blockIdx.x * 256 + tid;
  const int e0 = gid * EPT;
  const bool act = (e0 < NE);  // NE%EPT==0; only last block has idle threads

  int d[EPT];
  unsigned rec[EPT];
  if (act) {
    const int4* dp = (const int4*)(dst + e0);
    const int4* sp = (const int4*)(src + e0);
    const int4* ap = (const int4*)(ea + 3 * e0);
    int a[3 * EPT];
#pragma unroll
    for (int q = 0; q < (3 * EPT) / 4; ++q) {
      const int4 v = ap[q];
      a[4 * q + 0] = v.x; a[4 * q + 1] = v.y; a[4 * q + 2] = v.z; a[4 * q + 3] = v.w;
    }
#pragma unroll
    for (int q = 0; q < EPT / 4; ++q) {
      const int4 dv = dp[q];
      const int4 sv = sp[q];
      d[4 * q + 0] = dv.x; d[4 * q + 1] = dv.y; d[4 * q + 2] = dv.z; d[4 * q + 3] = dv.w;
      rec[4 * q + 0] = sv.x; rec[4 * q + 1] = sv.y; rec[4 * q + 2] = sv.z; rec[4 * q + 3] = sv.w;
    }
#pragma unroll
    for (int q = 0; q < EPT; ++q) {
      const unsigned cb = (unsigned)((a[3 * q] * 5 + a[3 * q + 1]) * 5 + a[3 * q + 2]);
      rec[q] |= (cb << 16) | ((unsigned)(d[q] & 255) << 23);
      atomicAdd(&lcnt[d[q] >> 8], 1);  // LDS
    }
  }
  __syncthreads();
  for (int i = tid; i < NB; i += 256)
    gbase[i] = atomicAdd(&bucketCnt[i], lcnt[i]);  // global, 196/block
  __syncthreads();
  if (act) {
#pragma unroll
    for (int q = 0; q < EPT; ++q) {
      const int b = d[q] >> 8;
      const int r = atomicAdd(&lcur[b], 1) + gbase[b];  // LDS rank + base
      if (r < CAP) staging[(size_t)b * CAP + r] = rec[q];
    }
  }
}

// ---------------------------------------------------------------------------
// K2: fine CSR within each bucket. One block per bucket: records -> LDS,
// 256-bin hist + scan -> exact begin/end per node, scatter inside the
// L2-resident 36 KB region (coalesced writeback).
// packed2 record = src | cb<<16 (23 bits, same as k_agg expects).
// ---------------------------------------------------------------------------
__global__ __launch_bounds__(256) void k_fine(const int* __restrict__ bucketCnt,
                                              const unsigned* __restrict__ staging,
                                              unsigned* __restrict__ packed2,
                                              int* __restrict__ beg,
                                              int* __restrict__ end) {
  __shared__ unsigned srec[CAP];      // 36 KB
  __shared__ int hist[256], off[256], cur[256];
  const int tid = threadIdx.x;
  const int b = blockIdx.x;
  const int base = b * CAP;
  const int cnt = min(bucketCnt[b], CAP);

  hist[tid] = 0; cur[tid] = 0;
  for (int i = tid; i < cnt; i += 256) srec[i] = staging[base + i];
  __syncthreads();
  for (int i = tid; i < cnt; i += 256) atomicAdd(&hist[srec[i] >> 23], 1);
  __syncthreads();
  // exclusive scan of hist -> off
  int v = hist[tid];
  off[tid] = v;
  __syncthreads();
  for (int s = 1; s < 256; s <<= 1) {
    const int u = (tid >= s) ? off[tid - s] : 0;
    __syncthreads();
    off[tid] += u;
    __syncthreads();
  }
  const int ex = off[tid] - v;
  __syncthreads();
  off[tid] = ex;
  __syncthreads();

  const int n = b * 256 + tid;
  if (n < NN) {
    beg[n] = base + off[tid];
    end[n] = base + off[tid] + hist[tid];
  }
  for (int i = tid; i < cnt; i += 256) {
    const unsigned u = srec[i];
    const int node = u >> 23;
    const int r = atomicAdd(&cur[node], 1);
    packed2[base + off[node] + r] = u & 0x7FFFFFu;
  }
}

// ---------------------------------------------------------------------------
// K3: per-node aggregation (exact CSR). 32 lanes/node, bf16 neighbor gather.
// ---------------------------------------------------------------------------
__global__ __launch_bounds__(256, 4) void k_agg(const float* __restrict__ x,
                                                const ushort* __restrict__ xh,
                                                const float* __restrict__ ctab,
                                                const float* __restrict__ epsp,
                                                const int* __restrict__ beg,
                                                const int* __restrict__ end,
                                                const unsigned* __restrict__ packed2,
                                                float* __restrict__ hbuf) {
  const int lane = threadIdx.x & 31;
  const int n = blockIdx.x * 8 + (threadIdx.x >> 5);  // 6250*8 = NN exactly
  const int col = lane << 2;

  const int jb = beg[n];
  const int je = end[n];
  float4 acc = make_float4(0.f, 0.f, 0.f, 0.f);

  for (int j0 = jb; j0 < je; j0 += 32) {
    const int rem = min(32, je - j0);
    const int pk = (j0 + lane < je) ? (int)packed2[j0 + lane] : 0;
    int t = 0;
    for (; t + 8 <= rem; t += 8) {
      unsigned p[8];
#pragma unroll
      for (int i = 0; i < 8; ++i) p[i] = (unsigned)__shfl(pk, t + i, 32);
      ushort4 xs[8];
#pragma unroll
      for (int i = 0; i < 8; ++i)
        xs[i] = *(const ushort4*)(xh + (size_t)(p[i] & 0xFFFF) * D + col);
#pragma unroll
      for (int i = 0; i < 8; ++i) {
        const float4 ev = *(const float4*)(ctab + ((p[i] >> 16) & 0x7F) * D + col);
        acc.x += fmaxf(bf2f(xs[i].x) + ev.x, 0.f);
        acc.y += fmaxf(bf2f(xs[i].y) + ev.y, 0.f);
        acc.z += fmaxf(bf2f(xs[i].z) + ev.z, 0.f);
        acc.w += fmaxf(bf2f(xs[i].w) + ev.w, 0.f);
      }
    }
    for (; t < rem; ++t) {
      const unsigned p = (unsigned)__shfl(pk, t, 32);
      const ushort4 xv = *(const ushort4*)(xh + (size_t)(p & 0xFFFF) * D + col);
      const float4 ev = *(const float4*)(ctab + ((p >> 16) & 0x7F) * D + col);
      acc.x += fmaxf(bf2f(xv.x) + ev.x, 0.f);
      acc.y += fmaxf(bf2f(xv.y) + ev.y, 0.f);
      acc.z += fmaxf(bf2f(xv.z) + ev.z, 0.f);
      acc.w += fmaxf(bf2f(xv.w) + ev.w, 0.f);
    }
  }

  const float eps1 = 1.0f + epsp[0];
  const float4 xv = *(const float4*)(x + (size_t)n * D + col);
  acc.x += eps1 * xv.x;
  acc.y += eps1 * xv.y;
  acc.z += eps1 * xv.z;
  acc.w += eps1 * xv.w;
  *(float4*)(hbuf + (size_t)n * D + col) = acc;
}

// ---------------------------------------------------------------------------
// K4: h1 = h @ W1 + b1 (in-place) + fused BN sum/sumsq. (unchanged control)
// ---------------------------------------------------------------------------
__global__ __launch_bounds__(256, 2) void k_gemm1(const float* __restrict__ hbuf,
                                                  const float* __restrict__ W1,
                                                  const float* __restrict__ b1,
                                                  float* __restrict__ h1,
                                                  float* __restrict__ gsum,
                                                  float* __restrict__ gsumsq) {
  __shared__ float shT[64 * 64];
  __shared__ float sW[64 * 128];

  const int tid = threadIdx.x;
  const int row0 = blockIdx.x * 64;
  const int cg = tid & 31;
  const int rt = tid >> 5;
  const int cbase = cg * 4;
  const int rbase = rt * 8;

  float4 acc[8];
  const float4 bias = *(const float4*)(b1 + cbase);
#pragma unroll
  for (int r = 0; r < 8; ++r) acc[r] = bias;

  for (int kh = 0; kh < 2; ++kh) {
    __syncthreads();
    for (int i = tid; i < 1024; i += 256) {
      const int r = i & 63;
      const int kc = (i >> 6) << 2;
      const int gr = row0 + r;
      float4 v = make_float4(0.f, 0.f, 0.f, 0.f);
      if (gr < NN) v = *(const float4*)(hbuf + (size_t)gr * D + kh * 64 + kc);
      shT[(kc + 0) * 64 + r] = v.x;
      shT[(kc + 1) * 64 + r] = v.y;
      shT[(kc + 2) * 64 + r] = v.z;
      shT[(kc + 3) * 64 + r] = v.w;
    }
    for (int i = tid; i < 2048; i += 256) {
      const int k = i >> 5;
      const int c4 = (i & 31) << 2;
      *(float4*)(sW + k * 128 + c4) = *(const float4*)(W1 + (size_t)(kh * 64 + k) * D + c4);
    }
    __syncthreads();
    for (int k = 0; k < 64; ++k) {
      const float4 a_lo = *(const float4*)(shT + k * 64 + rbase);
      const float4 a_hi = *(const float4*)(shT + k * 64 + rbase + 4);
      const float4 w = *(const float4*)(sW + k * 128 + cbase);
      fma4(acc[0], a_lo.x, w); fma4(acc[1], a_lo.y, w);
      fma4(acc[2], a_lo.z, w); fma4(acc[3], a_lo.w, w);
      fma4(acc[4], a_hi.x, w); fma4(acc[5], a_hi.y, w);
      fma4(acc[6], a_hi.z, w); fma4(acc[7], a_hi.w, w);
    }
  }

  float4 cs = make_float4(0.f, 0.f, 0.f, 0.f);
  float4 cq = make_float4(0.f, 0.f, 0.f, 0.f);
#pragma unroll
  for (int r = 0; r < 8; ++r) {
    const int gr = row0 + rbase + r;
    if (gr < NN) {
      *(float4*)(h1 + (size_t)gr * D + cbase) = acc[r];
      cs.x += acc[r].x; cs.y += acc[r].y; cs.z += acc[r].z; cs.w += acc[r].w;
      cq.x += acc[r].x * acc[r].x; cq.y += acc[r].y * acc[r].y;
      cq.z += acc[r].z * acc[r].z; cq.w += acc[r].w * acc[r].w;
    }
  }
  __syncthreads();
  float* ssum = shT;
  float* ssq = shT + 128;
  if (tid < 128) { ssum[tid] = 0.f; ssq[tid] = 0.f; }
  __syncthreads();
  atomicAdd(&ssum[cbase + 0], cs.x);
  atomicAdd(&ssum[cbase + 1], cs.y);
  atomicAdd(&ssum[cbase + 2], cs.z);
  atomicAdd(&ssum[cbase + 3], cs.w);
  atomicAdd(&ssq[cbase + 0], cq.x);
  atomicAdd(&ssq[cbase + 1], cq.y);
  atomicAdd(&ssq[cbase + 2], cq.z);
  atomicAdd(&ssq[cbase + 3], cq.w);
  __syncthreads();
  if (tid < 128) {
    atomicAdd(&gsum[tid], ssum[tid]);
    atomicAdd(&gsumsq[tid], ssq[tid]);
  }
}

// ---------------------------------------------------------------------------
// K5: out = relu(BN(h1)) @ W2 + b2. (unchanged control)
// ---------------------------------------------------------------------------
__global__ __launch_bounds__(256, 2) void k_gemm2(const float* __restrict__ hbuf,
                                                  const float* __restrict__ gsum,
                                                  const float* __restrict__ gsq,
                                                  const float* __restrict__ gamma,
                                                  const float* __restrict__ beta,
                                                  const float* __restrict__ W2,
                                                  const float* __restrict__ b2,
                                                  float* __restrict__ out) {
  __shared__ float shT[64 * 64];
  __shared__ float sW[64 * 128];

  const int tid = threadIdx.x;
  const int row0 = blockIdx.x * 64;
  const int cg = tid & 31;
  const int rt = tid >> 5;
  const int cbase = cg * 4;
  const int rbase = rt * 8;
  const float invN = 1.0f / (float)NN;

  float4 acc[8];
  const float4 bias = *(const float4*)(b2 + cbase);
#pragma unroll
  for (int r = 0; r < 8; ++r) acc[r] = bias;

  for (int kh = 0; kh < 2; ++kh) {
    __syncthreads();
    for (int i = tid; i < 1024; i += 256) {
      const int r = i & 63;
      const int kc = (i >> 6) << 2;
      const int gr = row0 + r;
      const int kk = kh * 64 + kc;
      const float4 gs = *(const float4*)(gsum + kk);
      const float4 gq = *(const float4*)(gsq + kk);
      const float4 gm = *(const float4*)(gamma + kk);
      const float4 bt = *(const float4*)(beta + kk);
      const float m0 = gs.x * invN, m1 = gs.y * invN, m2 = gs.z * invN, m3 = gs.w * invN;
      const float A0 = gm.x * rsqrtf(gq.x * invN - m0 * m0 + 1e-5f);
      const float A1 = gm.y * rsqrtf(gq.y * invN - m1 * m1 + 1e-5f);
      const float A2 = gm.z * rsqrtf(gq.z * invN - m2 * m2 + 1e-5f);
      const float A3 = gm.w * rsqrtf(gq.w * invN - m3 * m3 + 1e-5f);
      float4 v = make_float4(0.f, 0.f, 0.f, 0.f);
      if (gr < NN) {
        const float4 h = *(const float4*)(hbuf + (size_t)gr * D + kk);
        v.x = fmaxf(fmaf(h.x - m0, A0, bt.x), 0.f);
        v.y = fmaxf(fmaf(h.y - m1, A1, bt.y), 0.f);
        v.z = fmaxf(fmaf(h.z - m2, A2, bt.z), 0.f);
        v.w = fmaxf(fmaf(h.w - m3, A3, bt.w), 0.f);
      }
      shT[(kc + 0) * 64 + r] = v.x;
      shT[(kc + 1) * 64 + r] = v.y;
      shT[(kc + 2) * 64 + r] = v.z;
      shT[(kc + 3) * 64 + r] = v.w;
    }
    for (int i = tid; i < 2048; i += 256) {
      const int k = i >> 5;
      const int c4 = (i & 31) << 2;
      *(float4*)(sW + k * 128 + c4) = *(const float4*)(W2 + (size_t)(kh * 64 + k) * D + c4);
    }
    __syncthreads();
    for (int k = 0; k < 64; ++k) {
      const float4 a_lo = *(const float4*)(shT + k * 64 + rbase);
      const float4 a_hi = *(const float4*)(shT + k * 64 + rbase + 4);
      const float4 w = *(const float4*)(sW + k * 128 + cbase);
      fma4(acc[0], a_lo.x, w); fma4(acc[1], a_lo.y, w);
      fma4(acc[2], a_lo.z, w); fma4(acc[3], a_lo.w, w);
      fma4(acc[4], a_hi.x, w); fma4(acc[5], a_hi.y, w);
      fma4(acc[6], a_hi.z, w); fma4(acc[7], a_hi.w, w);
    }
  }

#pragma unroll
  for (int r = 0; r < 8; ++r) {
    const int gr = row0 + rbase + r;
    if (gr < NN) *(float4*)(out + (size_t)gr * D + cbase) = acc[r];
  }
}

extern "C" void kernel_launch(void* const* d_in, const int* in_sizes, int n_in,
                              void* d_out, int out_size, void* d_ws, size_t ws_size,
                              hipStream_t stream) {
  const float* x    = (const float*)d_in[0];
  const int* ea     = (const int*)d_in[1];
  const int* src    = (const int*)d_in[2];
  const int* dst    = (const int*)d_in[3];
  const float* bemb = (const float*)d_in[4];
  const float* epsp = (const float*)d_in[5];
  const float* W1   = (const float*)d_in[6];
  const float* b1   = (const float*)d_in[7];
  const float* gam  = (const float*)d_in[8];
  const float* bet  = (const float*)d_in[9];
  const float* W2   = (const float*)d_in[10];
  const float* b2   = (const float*)d_in[11];
  float* out = (float*)d_out;

  float* ws         = (float*)d_ws;
  float* hbuf       = ws;                                   // NN*D fp32
  int* bucketCnt    = (int*)(ws + (size_t)NN * D);          // NB   (zeroed)
  float* gsum       = ws + (size_t)NN * D + NB;             // 128  (zeroed)
  float* gsumsq     = gsum + D;                             // 128  (zeroed)
  int* beg          = (int*)(gsumsq + D);                   // NN
  int* endp         = beg + NN;                             // NN
  float* ctab       = (float*)(endp + NN);                  // 125*128
  ushort* xh        = (ushort*)(ctab + 125 * D);            // NN*D bf16
  unsigned* staging = (unsigned*)(xh + (size_t)NN * D);     // NB*CAP (7.2 MB)
  unsigned* packed2 = staging + (size_t)NB * CAP;           // NB*CAP (7.2 MB)

  hipMemsetAsync(bucketCnt, 0, (size_t)(NB + 2 * D) * sizeof(int), stream);

  k_half<<<(NN * D / 4 + 255) / 256, 256, 0, stream>>>(x, bemb, xh, ctab);
  k_bin<<<(NE / EPT + 255) / 256, 256, 0, stream>>>(dst, src, ea, bucketCnt, staging);
  k_fine<<<NB, 256, 0, stream>>>(bucketCnt, staging, packed2, beg, endp);
  k_agg<<<NN / 8, 256, 0, stream>>>(x, xh, ctab, epsp, beg, endp, packed2, hbuf);
  k_gemm1<<<(NN + 63) / 64, 256, 0, stream>>>(hbuf, W1, b1, hbuf, gsum, gsumsq);
  k_gemm2<<<(NN + 63) / 64, 256, 0, stream>>>(hbuf, gsum, gsumsq, gam, bet, W2, b2, out);
}